// Round 4
// baseline (7880.354 us; speedup 1.0000x reference)
//
#include <hip/hip_runtime.h>
#include <hip/hip_cooperative_groups.h>

namespace cg = cooperative_groups;

typedef unsigned short u16;
typedef unsigned int u32;
typedef __attribute__((ext_vector_type(8))) short short8;
typedef __attribute__((ext_vector_type(4))) float floatx4;

#define B_ 16
#define S_ 64
#define H_ 512
#define V_ 32000
#define G3 1536   // 3*H
#define TD 63     // T-1
#define MROWS 1008

__device__ __forceinline__ float b2f(u16 u) {
  union { u32 i; float f; } c; c.i = ((u32)u) << 16; return c.f;
}
__device__ __forceinline__ u16 f2b(float f) {
  union { float f; u32 i; } c; c.f = f;
  u32 u = c.i;
  return (u16)((u + 0x7FFFu + ((u >> 16) & 1u)) >> 16);  // RNE
}

// dot of 64 f32 weights with 64 f32 values (both 16B aligned)
__device__ __forceinline__ float dot64f(const float* __restrict__ w, const float* __restrict__ h) {
  float acc = 0.f;
#pragma unroll
  for (int u = 0; u < 16; ++u) {
    float4 wv = ((const float4*)w)[u];
    float4 hv = ((const float4*)h)[u];
    acc += wv.x * hv.x + wv.y * hv.y + wv.z * hv.z + wv.w * hv.w;
  }
  return acc;
}

// ---------------- embedding gather (f32 -> bf16) ----------------
__global__ void __launch_bounds__(256) gather_kernel(
    const int* __restrict__ x, const int* __restrict__ y,
    const float* __restrict__ emb_enc, const float* __restrict__ emb_dec,
    u16* __restrict__ ex, u16* __restrict__ ey)
{
  const int r = blockIdx.x, tid = threadIdx.x;
  if (r < B_ * S_) {                       // encoder row m = b*64+s
    int tok = x[r];
    float2 v = ((const float2*)(emb_enc + (size_t)tok * H_))[tid];
    ((u32*)(ex + (size_t)r * H_))[tid] = (u32)f2b(v.x) | ((u32)f2b(v.y) << 16);
  } else {                                 // decoder row m = t*16+b
    int m = r - B_ * S_;
    int t = m >> 4, b = m & 15;
    int tok = y[b * 64 + t];
    float2 v = ((const float2*)(emb_dec + (size_t)tok * H_))[tid];
    ((u32*)(ey + (size_t)m * H_))[tid] = (u32)f2b(v.x) | ((u32)f2b(v.y) << 16);
  }
}

// ---------------- bf16-MFMA GEMM: C = A @ B^T + bias ----------------
// A:[M,512] bf16 (K-contiguous), B:[N,512] FLOAT32 (K-contiguous, converted to
// bf16 on the fly during LDS staging), bias f32[N]
// MODE 0: C fp32 [M,N].  MODE 1: C fp32 into d_out, row remap m=t*16+b -> (b*63+t)
template <int MODE>
__global__ void __launch_bounds__(256) gemm_bt(
    const u16* __restrict__ A, const float* __restrict__ Bm,
    const float* __restrict__ bias, void* __restrict__ Cout, int M, int N)
{
  __shared__ u16 As[64 * 40];   // +8 pad breaks bank conflicts on b128 reads
  __shared__ u16 Bs[128 * 40];
  const int tid = threadIdx.x;
  const int wave = tid >> 6, lane = tid & 63;
  const int l15 = lane & 15, quad = lane >> 4;
  const int m0 = blockIdx.y * 64, n0 = blockIdx.x * 128;
  floatx4 acc[4][2] = {};

  for (int kk = 0; kk < 512; kk += 32) {
    // A tile: 64 rows x 32 cols bf16
    {
      int row = tid >> 2, ch = tid & 3;
      short8 v = {};
      int gm = m0 + row;
      if (gm < M) v = *(const short8*)(A + (size_t)gm * 512 + kk + ch * 8);
      *(short8*)(As + row * 40 + ch * 8) = v;
    }
    // B tile: 128 rows x 32 cols, f32 -> bf16 convert during staging
#pragma unroll
    for (int i = 0; i < 4; ++i) {
      int idx = tid + i * 256;          // 0..1023
      int row = idx >> 3, c4 = idx & 7; // 8 float4 per row
      int gn = n0 + row;
      float4 w = *(const float4*)(Bm + (size_t)gn * 512 + kk + c4 * 4);
      uint2 p;
      p.x = (u32)f2b(w.x) | ((u32)f2b(w.y) << 16);
      p.y = (u32)f2b(w.z) | ((u32)f2b(w.w) << 16);
      *(uint2*)(Bs + row * 40 + c4 * 4) = p;
    }
    __syncthreads();
    short8 af[4], bfr[2];
#pragma unroll
    for (int mt = 0; mt < 4; ++mt)
      af[mt] = *(const short8*)(As + (mt * 16 + l15) * 40 + quad * 8);
#pragma unroll
    for (int nt = 0; nt < 2; ++nt)
      bfr[nt] = *(const short8*)(Bs + (wave * 32 + nt * 16 + l15) * 40 + quad * 8);
#pragma unroll
    for (int mt = 0; mt < 4; ++mt)
#pragma unroll
      for (int nt = 0; nt < 2; ++nt)
        acc[mt][nt] = __builtin_amdgcn_mfma_f32_16x16x32_bf16(af[mt], bfr[nt], acc[mt][nt], 0, 0, 0);
    __syncthreads();
  }
#pragma unroll
  for (int mt = 0; mt < 4; ++mt) {
#pragma unroll
    for (int nt = 0; nt < 2; ++nt) {
      int gn = n0 + wave * 32 + nt * 16 + l15;
      float bv = bias[gn];
#pragma unroll
      for (int r = 0; r < 4; ++r) {
        int gm = m0 + mt * 16 + quad * 4 + r;  // C/D: col=lane&15, row=quad*4+reg
        if (gm < M) {
          float v = acc[mt][nt][r] + bv;
          if (MODE == 0) {
            ((float*)Cout)[(size_t)gm * N + gn] = v;
          } else {
            int tt = gm >> 4, bb = gm & 15;
            ((float*)Cout)[((size_t)bb * TD + tt) * V_ + gn] = v;
          }
        }
      }
    }
  }
}

// ---------------- cooperative recurrence (all weights f32) ----------------
struct RecArgs {
  const float* gi_enc;   // [B][S][1536]
  const float* gi_dec;   // [TD][B][1536]
  const float* Whh_e;    // [1536][512] f32
  const float* Whh_d;
  const float* bhh_e;    // [1536] f32
  const float* bhh_d;
  const float* Wc;       // [512][1024] f32
  const float* bc;       // [512] f32
  float* enc_out;        // [B][S][512]
  float* hbuf;           // [2][B][512]
  float* attn;           // [B][512]
  u16* D;                // [1008][512]  (row = t*16+b)
};

// one GRU step: 8192 tasks (b,j), 8 threads per task (K split 8x64)
__device__ __forceinline__ void gru_phase(
    const float* __restrict__ Whh, const float* __restrict__ bhh,
    const float* __restrict__ gi_step, int gi_bstride,
    const float* __restrict__ hcur, float* __restrict__ hnext,
    float* __restrict__ enc_row, float (*red)[32][8])
{
  const int tid = threadIdx.x;
  const int tl = tid >> 3, q = tid & 7;
  const int tau = blockIdx.x * 32 + tl;   // = j*16 + b
  const int j = tau >> 4, b = tau & 15;
  const float* h = hcur + b * H_ + q * 64;
  const float* wr = Whh + (size_t)j * H_ + q * 64;
  float ar = dot64f(wr, h);
  float az = dot64f(wr + 512 * H_, h);
  float an = dot64f(wr + 1024 * H_, h);
  red[0][tl][q] = ar; red[1][tl][q] = az; red[2][tl][q] = an;
  __syncthreads();
  if (q == 0) {
    float sr = 0.f, sz = 0.f, sn = 0.f;
#pragma unroll
    for (int u = 0; u < 8; ++u) { sr += red[0][tl][u]; sz += red[1][tl][u]; sn += red[2][tl][u]; }
    const float* girow = gi_step + (size_t)b * gi_bstride;
    float ir = girow[j], iz = girow[512 + j], inn = girow[1024 + j];
    float hr = sr + bhh[j];
    float hz = sz + bhh[512 + j];
    float hn = sn + bhh[1024 + j];
    float r = 1.f / (1.f + __expf(-(ir + hr)));
    float z = 1.f / (1.f + __expf(-(iz + hz)));
    float n = tanhf(inn + r * hn);
    float hp = hcur[b * H_ + j];
    float hv = (1.f - z) * n + z * hp;
    hnext[b * H_ + j] = hv;
    if (enc_row) enc_row[(size_t)b * (S_ * H_) + j] = hv;
  }
  __syncthreads();
}

__global__ void __launch_bounds__(256) rec_kernel(RecArgs a) {
  cg::grid_group grid = cg::this_grid();
  __shared__ float red[3][32][8];
  __shared__ float redB[64][4];
  __shared__ float wts[64];
  const int tid = threadIdx.x, bk = blockIdx.x;

  { // zero h0
    int i = bk * 256 + tid;
    if (i < B_ * H_) a.hbuf[i] = 0.f;
  }
  grid.sync();

  // ---- encoder: h_s stored in hbuf[(s+1)&1] ----
  for (int s = 0; s < S_; ++s) {
    const float* hc = a.hbuf + (s & 1) * (B_ * H_);
    float* hn = a.hbuf + ((s + 1) & 1) * (B_ * H_);
    gru_phase(a.Whh_e, a.bhh_e, a.gi_enc + (size_t)s * G3, S_ * G3,
              hc, hn, a.enc_out + (size_t)s * H_, red);
    grid.sync();
  }
  // ---- decoder step 0 h-update (reads h_enc in hbuf[0]) ----
  gru_phase(a.Whh_d, a.bhh_d, a.gi_dec, G3,
            a.hbuf, a.hbuf + (B_ * H_), nullptr, red);
  grid.sync();

  for (int t = 0; t < TD; ++t) {
    const float* hcurt = a.hbuf + ((t + 1) & 1) * (B_ * H_);  // h_{t+1}
    // ---- B1: attention (one block per batch) ----
    if (bk < B_) {
      const int b = bk;
      const int s = tid >> 2, q4 = tid & 3;
      const float* hb = hcurt + b * H_ + q4 * 128;
      const float* eo = a.enc_out + ((size_t)b * S_ + s) * H_ + q4 * 128;
      float acc = 0.f;
#pragma unroll 8
      for (int u = 0; u < 32; ++u) {
        float4 e = ((const float4*)eo)[u];
        float4 hh = ((const float4*)hb)[u];
        acc += e.x * hh.x + e.y * hh.y + e.z * hh.z + e.w * hh.w;
      }
      redB[s][q4] = acc;
      __syncthreads();
      if (tid < 64) {
        float v = redB[tid][0] + redB[tid][1] + redB[tid][2] + redB[tid][3];
        float m = v;
#pragma unroll
        for (int d = 1; d < 64; d <<= 1) m = fmaxf(m, __shfl_xor(m, d));
        float e = __expf(v - m);
        float sum = e;
#pragma unroll
        for (int d = 1; d < 64; d <<= 1) sum += __shfl_xor(sum, d);
        wts[tid] = e / sum;
      }
      __syncthreads();
      for (int jj = tid; jj < H_; jj += 256) {
        float acc2 = 0.f;
        const float* eob = a.enc_out + (size_t)b * (S_ * H_) + jj;
#pragma unroll 8
        for (int s2 = 0; s2 < S_; ++s2) acc2 += wts[s2] * eob[s2 * H_];
        a.attn[b * H_ + jj] = acc2;
      }
    }
    grid.sync();
    // ---- B2: d_t = tanh([h;attn] @ Wc^T + bc) ; merged with next h-update ----
    {
      const int tl = tid >> 3, q = tid & 7;
      const int tau = bk * 32 + tl;
      const int i = tau >> 4, b = tau & 15;
      const float* wch = a.Wc + (size_t)i * 1024 + q * 64;
      float acc = dot64f(wch, hcurt + b * H_ + q * 64)
                + dot64f(wch + 512, a.attn + b * H_ + q * 64);
      red[0][tl][q] = acc;
      __syncthreads();
      if (q == 0) {
        float sum = 0.f;
#pragma unroll
        for (int u = 0; u < 8; ++u) sum += red[0][tl][u];
        float dv = tanhf(sum + a.bc[i]);
        a.D[((size_t)t * B_ + b) * H_ + i] = f2b(dv);
      }
      __syncthreads();
    }
    if (t < TD - 1) {
      gru_phase(a.Whh_d, a.bhh_d, a.gi_dec + (size_t)(t + 1) * (B_ * G3), G3,
                hcurt, a.hbuf + (t & 1) * (B_ * H_), nullptr, red);
    }
    grid.sync();
  }
}

// ---------------- loss (f32 logits) ----------------
__global__ void __launch_bounds__(256) loss_rows_kernel(
    const float* __restrict__ logits, const int* __restrict__ y, float* __restrict__ nll)
{
  __shared__ float wred[4];
  const int m = blockIdx.x;               // m = t*16+b
  const int t = m >> 4, b = m & 15;
  const float* row = logits + ((size_t)b * TD + t) * V_;
  const int tid = threadIdx.x;
  const int lane = tid & 63, wave = tid >> 6;

  float mx = -1e30f;
  for (int c = tid; c < 8000; c += 256) {
    float4 v = ((const float4*)row)[c];
    mx = fmaxf(mx, fmaxf(fmaxf(v.x, v.y), fmaxf(v.z, v.w)));
  }
#pragma unroll
  for (int d = 1; d < 64; d <<= 1) mx = fmaxf(mx, __shfl_xor(mx, d));
  if (lane == 0) wred[wave] = mx;
  __syncthreads();
  mx = fmaxf(fmaxf(wred[0], wred[1]), fmaxf(wred[2], wred[3]));
  __syncthreads();

  float sum = 0.f;
  for (int c = tid; c < 8000; c += 256) {
    float4 v = ((const float4*)row)[c];
    sum += __expf(v.x - mx) + __expf(v.y - mx) + __expf(v.z - mx) + __expf(v.w - mx);
  }
#pragma unroll
  for (int d = 1; d < 64; d <<= 1) sum += __shfl_xor(sum, d);
  if (lane == 0) wred[wave] = sum;
  __syncthreads();
  if (tid == 0) {
    float stot = wred[0] + wred[1] + wred[2] + wred[3];
    int tok = y[b * 64 + t + 1];
    float tv = row[tok];
    nll[m] = mx + logf(stot) - tv;
  }
}

__global__ void __launch_bounds__(256) loss_final_kernel(const float* __restrict__ nll, float* __restrict__ out) {
  __shared__ float wred[4];
  const int tid = threadIdx.x;
  float s = 0.f;
  for (int i = tid; i < MROWS; i += 256) s += nll[i];
#pragma unroll
  for (int d = 1; d < 64; d <<= 1) s += __shfl_xor(s, d);
  if ((tid & 63) == 0) wred[tid >> 6] = s;
  __syncthreads();
  if (tid == 0) out[0] = (wred[0] + wred[1] + wred[2] + wred[3]) / 1008.f;
}

// ---------------- launch ----------------
extern "C" void kernel_launch(void* const* d_in, const int* in_sizes, int n_in,
                              void* d_out, int out_size, void* d_ws, size_t ws_size,
                              hipStream_t stream)
{
  const int*   x       = (const int*)d_in[0];
  const int*   y       = (const int*)d_in[1];
  const float* emb_enc = (const float*)d_in[2];
  const float* W_ih_e  = (const float*)d_in[3];
  const float* W_hh_e  = (const float*)d_in[4];
  const float* b_ih_e  = (const float*)d_in[5];
  const float* b_hh_e  = (const float*)d_in[6];
  const float* emb_dec = (const float*)d_in[7];
  const float* W_ih_d  = (const float*)d_in[8];
  const float* W_hh_d  = (const float*)d_in[9];
  const float* b_ih_d  = (const float*)d_in[10];
  const float* b_hh_d  = (const float*)d_in[11];
  const float* W_c     = (const float*)d_in[12];
  const float* b_c     = (const float*)d_in[13];
  const float* W_out   = (const float*)d_in[14];
  const float* b_out   = (const float*)d_in[15];

  // ws layout: identical footprint to the round-1-proven 17,797,056 bytes
  char* ws = (char*)d_ws;
  float* gi_enc  = (float*)(ws + 0);          //  6,291,456 B
  float* gi_dec  = (float*)(ws + 6291456);    //  6,193,152 B
  float* enc_out = (float*)(ws + 12484608);   //  2,097,152 B
  float* hbuf    = (float*)(ws + 14581760);   //     65,536 B
  float* attn    = (float*)(ws + 14647296);   //     32,768 B
  u16* embx      = (u16*)(ws + 14680064);     //  1,048,576 B
  u16* emby      = (u16*)(ws + 15728640);     //  1,032,192 B
  u16* Dm        = (u16*)(ws + 16760832);     //  1,032,192 B
  float* nll     = (float*)(ws + 17793024);   //      4,032 B  (end 17,797,056)

  gather_kernel<<<dim3(B_ * S_ + MROWS), dim3(256), 0, stream>>>(x, y, emb_enc, emb_dec, embx, emby);

  gemm_bt<0><<<dim3(12, 16), dim3(256), 0, stream>>>(embx, W_ih_e, b_ih_e, (void*)gi_enc, 1024, G3);
  gemm_bt<0><<<dim3(12, 16), dim3(256), 0, stream>>>(emby, W_ih_d, b_ih_d, (void*)gi_dec, MROWS, G3);

  RecArgs ra{gi_enc, gi_dec, W_hh_e, W_hh_d, b_hh_e, b_hh_d, W_c, b_c, enc_out, hbuf, attn, Dm};
  void* kargs[] = {(void*)&ra};
  hipLaunchCooperativeKernel(reinterpret_cast<const void*>(&rec_kernel),
                             dim3(256), dim3(256), kargs, 0, stream);

  gemm_bt<1><<<dim3(250, 16), dim3(256), 0, stream>>>(Dm, W_out, b_out, d_out, MROWS, V_);
  loss_rows_kernel<<<dim3(MROWS), dim3(256), 0, stream>>>((const float*)d_out, y, nll);
  loss_final_kernel<<<dim3(1), dim3(256), 0, stream>>>(nll, ((float*)d_out) + (size_t)MROWS * V_);
}

// Round 5
// 5377.294 us; speedup vs baseline: 1.4655x; 1.4655x over previous
//
#include <hip/hip_runtime.h>

typedef unsigned short u16;
typedef unsigned int u32;
typedef __attribute__((ext_vector_type(8))) short short8;
typedef __attribute__((ext_vector_type(4))) float floatx4;

#define B_ 16
#define S_ 64
#define H_ 512
#define V_ 32000
#define G3 1536   // 3*H
#define TD 63     // T-1
#define MROWS 1008

__device__ __forceinline__ float b2f(u16 u) {
  union { u32 i; float f; } c; c.i = ((u32)u) << 16; return c.f;
}
__device__ __forceinline__ u16 f2b(float f) {
  union { float f; u32 i; } c; c.f = f;
  u32 u = c.i;
  return (u16)((u + 0x7FFFu + ((u >> 16) & 1u)) >> 16);  // RNE
}

// ---------------- embedding gather (f32 -> bf16) ----------------
__global__ void __launch_bounds__(256) gather_kernel(
    const int* __restrict__ x, const int* __restrict__ y,
    const float* __restrict__ emb_enc, const float* __restrict__ emb_dec,
    u16* __restrict__ ex, u16* __restrict__ ey)
{
  const int r = blockIdx.x, tid = threadIdx.x;
  if (r < B_ * S_) {                       // encoder row m = b*64+s
    int tok = x[r];
    float2 v = ((const float2*)(emb_enc + (size_t)tok * H_))[tid];
    ((u32*)(ex + (size_t)r * H_))[tid] = (u32)f2b(v.x) | ((u32)f2b(v.y) << 16);
  } else {                                 // decoder row m = t*16+b
    int m = r - B_ * S_;
    int t = m >> 4, b = m & 15;
    int tok = y[b * 64 + t];
    float2 v = ((const float2*)(emb_dec + (size_t)tok * H_))[tid];
    ((u32*)(ey + (size_t)m * H_))[tid] = (u32)f2b(v.x) | ((u32)f2b(v.y) << 16);
  }
}

// ---------------- f32 transpose: dst[c][r] = src[r][c], dims % 32 == 0 ----------------
__global__ void __launch_bounds__(256) transpose_kernel(
    const float* __restrict__ src, float* __restrict__ dst, int rows, int cols)
{
  __shared__ float tile[32][33];
  const int tx = threadIdx.x & 31, ty = threadIdx.x >> 5;   // 32 x 8
  const int r0 = blockIdx.y * 32, c0 = blockIdx.x * 32;
#pragma unroll
  for (int i = 0; i < 4; ++i)
    tile[ty + i * 8][tx] = src[(size_t)(r0 + ty + i * 8) * cols + c0 + tx];
  __syncthreads();
#pragma unroll
  for (int i = 0; i < 4; ++i)
    dst[(size_t)(c0 + ty + i * 8) * rows + r0 + tx] = tile[tx][ty + i * 8];
}

// ---------------- bf16-MFMA GEMM: C = A @ B^T + bias ----------------
// A:[M,512] bf16, B:[N,512] f32 (converted to bf16 while staging), bias f32[N]
// MODE 0: C fp32 [M,N].  MODE 1: C fp32 into d_out, row remap m=t*16+b -> (b*63+t)
template <int MODE>
__global__ void __launch_bounds__(256) gemm_bt(
    const u16* __restrict__ A, const float* __restrict__ Bm,
    const float* __restrict__ bias, void* __restrict__ Cout, int M, int N)
{
  __shared__ u16 As[64 * 40];
  __shared__ u16 Bs[128 * 40];
  const int tid = threadIdx.x;
  const int wave = tid >> 6, lane = tid & 63;
  const int l15 = lane & 15, quad = lane >> 4;
  const int m0 = blockIdx.y * 64, n0 = blockIdx.x * 128;
  floatx4 acc[4][2] = {};

  for (int kk = 0; kk < 512; kk += 32) {
    {
      int row = tid >> 2, ch = tid & 3;
      short8 v = {};
      int gm = m0 + row;
      if (gm < M) v = *(const short8*)(A + (size_t)gm * 512 + kk + ch * 8);
      *(short8*)(As + row * 40 + ch * 8) = v;
    }
#pragma unroll
    for (int i = 0; i < 4; ++i) {
      int idx = tid + i * 256;
      int row = idx >> 3, c4 = idx & 7;
      int gn = n0 + row;
      float4 w = *(const float4*)(Bm + (size_t)gn * 512 + kk + c4 * 4);
      uint2 p;
      p.x = (u32)f2b(w.x) | ((u32)f2b(w.y) << 16);
      p.y = (u32)f2b(w.z) | ((u32)f2b(w.w) << 16);
      *(uint2*)(Bs + row * 40 + c4 * 4) = p;
    }
    __syncthreads();
    short8 af[4], bfr[2];
#pragma unroll
    for (int mt = 0; mt < 4; ++mt)
      af[mt] = *(const short8*)(As + (mt * 16 + l15) * 40 + quad * 8);
#pragma unroll
    for (int nt = 0; nt < 2; ++nt)
      bfr[nt] = *(const short8*)(Bs + (wave * 32 + nt * 16 + l15) * 40 + quad * 8);
#pragma unroll
    for (int mt = 0; mt < 4; ++mt)
#pragma unroll
      for (int nt = 0; nt < 2; ++nt)
        acc[mt][nt] = __builtin_amdgcn_mfma_f32_16x16x32_bf16(af[mt], bfr[nt], acc[mt][nt], 0, 0, 0);
    __syncthreads();
  }
#pragma unroll
  for (int mt = 0; mt < 4; ++mt) {
#pragma unroll
    for (int nt = 0; nt < 2; ++nt) {
      int gn = n0 + wave * 32 + nt * 16 + l15;
      float bv = bias[gn];
#pragma unroll
      for (int r = 0; r < 4; ++r) {
        int gm = m0 + mt * 16 + quad * 4 + r;  // C/D: col=lane&15, row=quad*4+reg
        if (gm < M) {
          float v = acc[mt][nt][r] + bv;
          if (MODE == 0) {
            ((float*)Cout)[(size_t)gm * N + gn] = v;
          } else {
            int tt = gm >> 4, bb = gm & 15;
            ((float*)Cout)[((size_t)bb * TD + tt) * V_ + gn] = v;
          }
        }
      }
    }
  }
}

// ---------------- per-batch recurrence: 16 blocks x 512 threads, NO grid sync ----------------
struct RecArgs {
  const float* gi_enc;   // [1024][1536]  row = b*64+s
  const float* gi_dec;   // [1008][1536]  row = t*16+b
  const float* WtE;      // [512][1536]   transposed W_hh_e (k-major)
  const float* WtD;      // [512][1536]
  const float* WcT;      // [1024][512]   transposed W_c
  const float* bhh_e;    // [1536]
  const float* bhh_d;
  const float* bc;       // [512]
  float* enc_out;        // [B][S][512]
  u16* D;                // [1008][512]   row = t*16+b
};

// GRU gate GEMV + pointwise update; h, garr in LDS. Threads 0..383 compute, all sync.
__device__ __forceinline__ void gru_step(
    const float* __restrict__ Wt, const float* __restrict__ bhh,
    const float* __restrict__ girow, float* __restrict__ h,
    float* __restrict__ garr, float* __restrict__ enc_row)
{
  const int tid = threadIdx.x;
  if (tid < 384) {
    const float* p = Wt + 4 * tid;             // column offset, row stride 1536
    floatx4 acc = {0.f, 0.f, 0.f, 0.f};
#pragma unroll 2
    for (int k = 0; k < 512; k += 4) {
      float4 hv = *(const float4*)(h + k);
      float4 w0 = *(const float4*)(p);
      float4 w1 = *(const float4*)(p + 1536);
      float4 w2 = *(const float4*)(p + 3072);
      float4 w3 = *(const float4*)(p + 4608);
      acc[0] += w0.x * hv.x + w1.x * hv.y + w2.x * hv.z + w3.x * hv.w;
      acc[1] += w0.y * hv.x + w1.y * hv.y + w2.y * hv.z + w3.y * hv.w;
      acc[2] += w0.z * hv.x + w1.z * hv.y + w2.z * hv.z + w3.z * hv.w;
      acc[3] += w0.w * hv.x + w1.w * hv.y + w2.w * hv.z + w3.w * hv.w;
      p += 4 * 1536;
    }
    *(floatx4*)(garr + 4 * tid) = acc;
  }
  __syncthreads();
  {
    const int j = tid;                          // 512 threads, one output each
    float gr = garr[j]        + bhh[j];
    float gz = garr[512 + j]  + bhh[512 + j];
    float gn = garr[1024 + j] + bhh[1024 + j];
    float r = 1.f / (1.f + __expf(-(girow[j] + gr)));
    float z = 1.f / (1.f + __expf(-(girow[512 + j] + gz)));
    float n = tanhf(girow[1024 + j] + r * gn);
    float hv = (1.f - z) * n + z * h[j];
    h[j] = hv;
    if (enc_row) enc_row[j] = hv;
  }
  __syncthreads();
}

__global__ void __launch_bounds__(512) rec_kernel(RecArgs a) {
  __shared__ float h[512];
  __shared__ float garr[1536];
  __shared__ float attnS[512];
  __shared__ float sc[64][9];
  __shared__ float wts[64];
  __shared__ floatx4 wcred[4][128];
  const int b = blockIdx.x;
  const int tid = threadIdx.x;

  h[tid] = 0.f;
  __syncthreads();

  // ---- encoder ----
  for (int s = 0; s < S_; ++s) {
    gru_step(a.WtE, a.bhh_e, a.gi_enc + ((size_t)b * 64 + s) * G3,
             h, garr, a.enc_out + ((size_t)b * 64 + s) * H_);
  }

  // ---- decoder ----
  for (int t = 0; t < TD; ++t) {
    // h-update
    gru_step(a.WtD, a.bhh_d, a.gi_dec + ((size_t)t * 16 + b) * G3,
             h, garr, nullptr);

    // attention scores: 64 s x 8 partials
    {
      const int sA = tid >> 3, q = tid & 7;
      const float* eo = a.enc_out + ((size_t)b * 64 + sA) * H_ + q * 64;
      const float* hq = h + q * 64;
      float acc = 0.f;
#pragma unroll
      for (int u = 0; u < 16; ++u) {
        float4 e = ((const float4*)eo)[u];
        float4 hh = ((const float4*)hq)[u];
        acc += e.x * hh.x + e.y * hh.y + e.z * hh.z + e.w * hh.w;
      }
      sc[sA][q] = acc;
    }
    __syncthreads();
    if (tid < 64) {
      float v = 0.f;
#pragma unroll
      for (int u = 0; u < 8; ++u) v += sc[tid][u];
      float m = v;
#pragma unroll
      for (int d = 1; d < 64; d <<= 1) m = fmaxf(m, __shfl_xor(m, d));
      float e = __expf(v - m);
      float sum = e;
#pragma unroll
      for (int d = 1; d < 64; d <<= 1) sum += __shfl_xor(sum, d);
      wts[tid] = e / sum;
    }
    __syncthreads();
    // attn[j] = sum_s wts[s] * enc_out[b][s][j]
    {
      const int j = tid;
      const float* eob = a.enc_out + (size_t)b * (S_ * H_) + j;
      float acc = 0.f;
#pragma unroll 8
      for (int s2 = 0; s2 < S_; ++s2) acc += wts[s2] * eob[s2 * H_];
      attnS[j] = acc;
    }
    __syncthreads();
    // d = tanh([h; attn] @ Wc^T + bc) via WcT[c][i]; 4 c-chunks x 128 i-quads
    {
      const int cc = tid >> 7, i0 = (tid & 127) * 4;
      const float* src = (cc < 2) ? (h + cc * 256) : (attnS + (cc - 2) * 256);
      const float* p = a.WcT + (size_t)(cc * 256) * 512 + i0;
      floatx4 acc = {0.f, 0.f, 0.f, 0.f};
#pragma unroll 2
      for (int c4 = 0; c4 < 256; c4 += 4) {
        float4 hv = *(const float4*)(src + c4);
        float4 w0 = *(const float4*)(p);
        float4 w1 = *(const float4*)(p + 512);
        float4 w2 = *(const float4*)(p + 1024);
        float4 w3 = *(const float4*)(p + 1536);
        acc[0] += w0.x * hv.x + w1.x * hv.y + w2.x * hv.z + w3.x * hv.w;
        acc[1] += w0.y * hv.x + w1.y * hv.y + w2.y * hv.z + w3.y * hv.w;
        acc[2] += w0.z * hv.x + w1.z * hv.y + w2.z * hv.z + w3.z * hv.w;
        acc[3] += w0.w * hv.x + w1.w * hv.y + w2.w * hv.z + w3.w * hv.w;
        p += 4 * 512;
      }
      wcred[cc][tid & 127] = acc;
    }
    __syncthreads();
    if (tid < 128) {
      floatx4 d4 = wcred[0][tid];
#pragma unroll
      for (int u = 1; u < 4; ++u) {
        d4[0] += wcred[u][tid][0]; d4[1] += wcred[u][tid][1];
        d4[2] += wcred[u][tid][2]; d4[3] += wcred[u][tid][3];
      }
      const int i0 = tid * 4;
      ushort4 o;
      o.x = f2b(tanhf(d4[0] + a.bc[i0 + 0]));
      o.y = f2b(tanhf(d4[1] + a.bc[i0 + 1]));
      o.z = f2b(tanhf(d4[2] + a.bc[i0 + 2]));
      o.w = f2b(tanhf(d4[3] + a.bc[i0 + 3]));
      *(ushort4*)(a.D + ((size_t)t * 16 + b) * H_ + i0) = o;
    }
    __syncthreads();
  }
}

// ---------------- loss (f32 logits) ----------------
__global__ void __launch_bounds__(256) loss_rows_kernel(
    const float* __restrict__ logits, const int* __restrict__ y, float* __restrict__ nll)
{
  __shared__ float wred[4];
  const int m = blockIdx.x;               // m = t*16+b
  const int t = m >> 4, b = m & 15;
  const float* row = logits + ((size_t)b * TD + t) * V_;
  const int tid = threadIdx.x;
  const int lane = tid & 63, wave = tid >> 6;

  float mx = -1e30f;
  for (int c = tid; c < 8000; c += 256) {
    float4 v = ((const float4*)row)[c];
    mx = fmaxf(mx, fmaxf(fmaxf(v.x, v.y), fmaxf(v.z, v.w)));
  }
#pragma unroll
  for (int d = 1; d < 64; d <<= 1) mx = fmaxf(mx, __shfl_xor(mx, d));
  if (lane == 0) wred[wave] = mx;
  __syncthreads();
  mx = fmaxf(fmaxf(wred[0], wred[1]), fmaxf(wred[2], wred[3]));
  __syncthreads();

  float sum = 0.f;
  for (int c = tid; c < 8000; c += 256) {
    float4 v = ((const float4*)row)[c];
    sum += __expf(v.x - mx) + __expf(v.y - mx) + __expf(v.z - mx) + __expf(v.w - mx);
  }
#pragma unroll
  for (int d = 1; d < 64; d <<= 1) sum += __shfl_xor(sum, d);
  if (lane == 0) wred[wave] = sum;
  __syncthreads();
  if (tid == 0) {
    float stot = wred[0] + wred[1] + wred[2] + wred[3];
    int tok = y[b * 64 + t + 1];
    nll[m] = mx + logf(stot) - row[tok];
  }
}

__global__ void __launch_bounds__(256) loss_final_kernel(const float* __restrict__ nll, float* __restrict__ out) {
  __shared__ float wred[4];
  const int tid = threadIdx.x;
  float s = 0.f;
  for (int i = tid; i < MROWS; i += 256) s += nll[i];
#pragma unroll
  for (int d = 1; d < 64; d <<= 1) s += __shfl_xor(s, d);
  if ((tid & 63) == 0) wred[tid >> 6] = s;
  __syncthreads();
  if (tid == 0) out[0] = (wred[0] + wred[1] + wred[2] + wred[3]) / 1008.f;
}

// ---------------- launch ----------------
extern "C" void kernel_launch(void* const* d_in, const int* in_sizes, int n_in,
                              void* d_out, int out_size, void* d_ws, size_t ws_size,
                              hipStream_t stream)
{
  const int*   x       = (const int*)d_in[0];
  const int*   y       = (const int*)d_in[1];
  const float* emb_enc = (const float*)d_in[2];
  const float* W_ih_e  = (const float*)d_in[3];
  const float* W_hh_e  = (const float*)d_in[4];
  const float* b_ih_e  = (const float*)d_in[5];
  const float* b_hh_e  = (const float*)d_in[6];
  const float* emb_dec = (const float*)d_in[7];
  const float* W_ih_d  = (const float*)d_in[8];
  const float* W_hh_d  = (const float*)d_in[9];
  const float* b_ih_d  = (const float*)d_in[10];
  const float* b_hh_d  = (const float*)d_in[11];
  const float* W_c     = (const float*)d_in[12];
  const float* b_c     = (const float*)d_in[13];
  const float* W_out   = (const float*)d_in[14];
  const float* b_out   = (const float*)d_in[15];

  // ws layout: proven 17,797,056-byte footprint
  char* ws = (char*)d_ws;
  float* gi_enc  = (float*)(ws + 0);          //  6,291,456 B
  float* gi_dec  = (float*)(ws + 6291456);    //  6,193,152 B
  float* enc_out = (float*)(ws + 12484608);   //  2,097,152 B
  u16* embx      = (u16*)(ws + 14680064);     //  1,048,576 B
  u16* emby      = (u16*)(ws + 15728640);     //  1,032,192 B
  u16* Dm        = (u16*)(ws + 16760832);     //  1,032,192 B
  float* nll     = (float*)(ws + 17793024);   //      4,032 B  (end 17,797,056)

  // transposed weights live in d_out's first 8.4 MB — free scratch until
  // gemm_bt<1> (which runs after rec_kernel) overwrites it with logits.
  float* WtE = (float*)d_out;                 // 512*1536 f32 = 3,145,728 B
  float* WtD = WtE + 512 * 1536;              // 3,145,728 B
  float* WcT = WtD + 512 * 1536;              // 1024*512 f32 = 2,097,152 B (end 8,388,608)

  transpose_kernel<<<dim3(16, 48), dim3(256), 0, stream>>>(W_hh_e, WtE, G3, H_);
  transpose_kernel<<<dim3(16, 48), dim3(256), 0, stream>>>(W_hh_d, WtD, G3, H_);
  transpose_kernel<<<dim3(32, 16), dim3(256), 0, stream>>>(W_c, WcT, H_, 1024);

  gather_kernel<<<dim3(B_ * S_ + MROWS), dim3(256), 0, stream>>>(x, y, emb_enc, emb_dec, embx, emby);

  gemm_bt<0><<<dim3(12, 16), dim3(256), 0, stream>>>(embx, W_ih_e, b_ih_e, (void*)gi_enc, 1024, G3);
  gemm_bt<0><<<dim3(12, 16), dim3(256), 0, stream>>>(emby, W_ih_d, b_ih_d, (void*)gi_dec, MROWS, G3);

  RecArgs ra{gi_enc, gi_dec, WtE, WtD, WcT, b_hh_e, b_hh_d, b_c, enc_out, Dm};
  rec_kernel<<<dim3(B_), dim3(512), 0, stream>>>(ra);

  gemm_bt<1><<<dim3(250, 16), dim3(256), 0, stream>>>(Dm, W_out, b_out, d_out, MROWS, V_);
  loss_rows_kernel<<<dim3(MROWS), dim3(256), 0, stream>>>((const float*)d_out, y, nll);
  loss_final_kernel<<<dim3(1), dim3(256), 0, stream>>>(nll, ((float*)d_out) + (size_t)MROWS * V_);
}